// Round 11
// baseline (191.299 us; speedup 1.0000x reference)
//
#include <hip/hip_runtime.h>
#include <math.h>
#include <stdint.h>

// Problem constants (static per reference):
//   B=32, N_ATOMS=128, C=25 (rep 2,2,0), RADIUS=8, MAX_NEIGHBORS=32
#define NATOMS   128
#define NCELLS   25
#define NCAND    (NATOMS * NCELLS)   // 3200 candidates per center atom
#define NGRP     (NCAND / 4)         // 800 float4 groups along f = j*25+c
#define MAXNB    32
#define R2       64.0f
#define BLK      256
#define KEYCAP   192
#define TODOCAP  256
#define DCUT     6.25f               // close-candidate radius^2 (r=2.5A); even for
                                     // z-slab boundary centers expected ~65 close
                                     // candidates >> 32 (density ~2 atoms/A^3)

// d2 chain replicated exactly as the reference (no FMA contraction):
// dv = (pos_j - pos_i) + off ; d2 = (dx*dx + dy*dy) + dz*dz
__device__ __forceinline__ float d2_exact(float4 p, float4 ctr, float4 o) {
    float dx = __fadd_rn(__fsub_rn(p.x, ctr.x), o.x);
    float dy = __fadd_rn(__fsub_rn(p.y, ctr.y), o.y);
    float dz = __fadd_rn(__fsub_rn(p.z, ctr.z), o.z);
    return __fadd_rn(__fadd_rn(__fmul_rn(dx,dx), __fmul_rn(dy,dy)),
                     __fmul_rn(dz,dz));
}

// 4096 blocks, one center each (~17 KB LDS -> 8 blocks/CU).
// R10 "optimistic streaming": whenever >=32 candidates lie within DCUT, the
// 32-NN cutoff K is below DCUT, so every group of 4 candidates that contains
// no close candidate has all-zero outputs INDEPENDENT of K -> store those
// zeros immediately during pass 1 (stores overlap all compute/selection,
// fill-style). Only the <=192 close-containing groups wait for K (tiny
// epilogue). Fallback (close count <32 or >KEYCAP, or total within <=32 —
// never at this density): histogram selection + full rewrite of all groups
// (valid: __syncthreads' vmcnt(0) drain orders rewrite after the optimistic
// stores). Exact stable cutoff key = (d2 bits << 32 | flat f), matching jnp
// stable argsort tie-break.
// Lessons kept: no fenced/scoped atomics (R5: per-block L2 flushes), no
// hipMemsetAsync graph node (R8: +20 us replay) -> reduce_counts 2nd kernel.
__global__ __launch_bounds__(BLK) void graph_kernel(
    const float* __restrict__ pos, const float* __restrict__ cell,
    float* __restrict__ out_dist, float* __restrict__ out_ctype,
    float* __restrict__ out_mask, float* __restrict__ ws_counts)
{
    __shared__ float4 s_pos4[NATOMS];
    __shared__ float4 s_off4[NCELLS];
    __shared__ float  s_ct[NCELLS];
    __shared__ float  s_d2[NCAND];             // inf where not within
    __shared__ unsigned long long s_keys[KEYCAP];
    __shared__ unsigned short s_todo[TODOCAP];
    __shared__ unsigned s_hist[256];           // fallback only
    __shared__ unsigned s_wtot[4];
    __shared__ int s_wred[4];
    __shared__ unsigned s_cnt, s_cnt2, s_ntodo;
    __shared__ int s_tot, s_binsel, s_need;
    __shared__ unsigned long long s_K;

    const int bi   = blockIdx.x;       // b*128 + i
    const int b    = bi >> 7;
    const int i    = bi & 127;
    const int tid  = threadIdx.x;
    const int lane = tid & 63;
    const int w    = tid >> 6;

    // ---- stage inputs into LDS (disjoint thread ranges) ----
    if (tid < NATOMS) {
        const float* p = pos + (b * NATOMS + tid) * 3;
        s_pos4[tid] = make_float4(p[0], p[1], p[2], 0.0f);
    }
    if (tid >= 160 && tid < 160 + NCELLS) {
        int c = tid - 160;
        float ux = (float)(c / 5 - 2);
        float uy = (float)(c % 5 - 2);
        // off = ux*row0 + uy*row1; products exact (|u|<=2), one rounded add.
        float ox = __fadd_rn(__fmul_rn(ux, cell[b*9+0]), __fmul_rn(uy, cell[b*9+3]));
        float oy = __fadd_rn(__fmul_rn(ux, cell[b*9+1]), __fmul_rn(uy, cell[b*9+4]));
        float oz = __fadd_rn(__fmul_rn(ux, cell[b*9+2]), __fmul_rn(uy, cell[b*9+5]));
        s_off4[c] = make_float4(ox, oy, oz, 0.0f);
        // ct = (ux+2)*5 + (uy+2)*5 (mults=[5,5,1] quirk per reference)
        s_ct[c] = (float)(5 * (c / 5) + 5 * (c % 5));
    }
    if (tid == 0) {
        s_cnt = 0; s_cnt2 = 0; s_ntodo = 0;
        s_binsel = -1; s_need = 0; s_K = ~0ULL;
    }
    __syncthreads();

    const float4 ctr = s_pos4[i];
    const long long base = (long long)bi * NGRP;
    float4* o0 = (float4*)out_dist  + base;
    float4* o1 = (float4*)out_ctype + base;
    float4* o2 = (float4*)out_mask  + base;
    const float4 z4 = make_float4(0.f, 0.f, 0.f, 0.f);

    // ---- pass 1: d2 -> s_d2, within count, collect close keys, and
    //      optimistically stream zero outputs for close-free groups ----
    int nwithin = 0;
    #pragma unroll 1
    for (int k = 0; k < 4; k++) {
        int g = tid + k * BLK;
        if (g >= NGRP) continue;       // k==3 only tid<32 (wave 0 partial)
        int f0 = g * 4;
        int j = f0 / 25;               // magic-div once per group
        int c = f0 - j * 25;
        float d2e[4];
        bool cl[4];
        bool anyclose = false;
        #pragma unroll
        for (int e = 0; e < 4; e++) {
            float d2 = d2_exact(s_pos4[j], ctr, s_off4[c]);
            bool within = (d2 <= R2) && (d2 > 1e-4f);
            d2e[e] = within ? d2 : __builtin_inff();
            nwithin += within;
            cl[e] = within && (d2 < DCUT);
            anyclose |= cl[e];
            c++; if (c == 25) { c = 0; j++; }
        }
        ((float4*)s_d2)[g] = make_float4(d2e[0], d2e[1], d2e[2], d2e[3]);
        #pragma unroll
        for (int e = 0; e < 4; e++) {
            unsigned long long mb = __ballot(cl[e]);
            if (mb) {
                unsigned cnt = (unsigned)__popcll(mb);
                unsigned kb = 0;
                if (lane == 0) kb = atomicAdd(&s_cnt, cnt);
                kb = __shfl(kb, 0);
                if (cl[e]) {
                    unsigned p = kb + (unsigned)__popcll(mb & ((1ULL << lane) - 1ULL));
                    if (p < KEYCAP)
                        s_keys[p] = ((unsigned long long)__float_as_uint(d2e[e]) << 32)
                                    | (unsigned)(f0 + e);
                }
            }
        }
        if (anyclose) {
            unsigned u = atomicAdd(&s_ntodo, 1u);
            if (u < TODOCAP) s_todo[u] = (unsigned short)g;
        } else {
            o0[g] = z4; o1[g] = z4; o2[g] = z4;   // final values, K-independent
        }
    }
    for (int o = 32; o; o >>= 1) nwithin += __shfl_down(nwithin, o);
    if (lane == 0) s_wred[w] = nwithin;
    __syncthreads();
    if (tid == 0) {
        int tot = s_wred[0] + s_wred[1] + s_wred[2] + s_wred[3];
        s_tot = tot;
        ws_counts[bi] = (float)(tot < MAXNB ? tot : MAXNB);
    }
    __syncthreads();

    const unsigned m = s_cnt;
    const bool fast = (s_tot > MAXNB) && (m >= MAXNB) && (m <= KEYCAP)
                      && (s_ntodo <= TODOCAP);

    if (fast) {
        // ---- rank the ~131 close keys; rank 31 = exact stable cutoff ----
        for (unsigned p = tid; p < m; p += BLK) {
            unsigned long long kp = s_keys[p];
            int r = 0;
            for (unsigned q = 0; q < m; q++) r += (s_keys[q] < kp);
            if (r == MAXNB - 1) s_K = kp;       // keys distinct -> unique
        }
        __syncthreads();
        const unsigned long long K = s_K;
        // ---- mini-epilogue: only the close-containing groups need K ----
        const int nt = (int)s_ntodo;
        for (int u = tid; u < nt; u += BLK) {
            int g = s_todo[u];
            int f0 = g * 4;
            float4 dq = ((const float4*)s_d2)[g];
            int c = f0 % NCELLS;
            float4 r0, r1, r2;
            #pragma unroll
            for (int e = 0; e < 4; e++) {
                float d2 = (&dq.x)[e];
                bool within = (d2 <= R2);
                unsigned long long key =
                    ((unsigned long long)__float_as_uint(d2) << 32)
                    | (unsigned)(f0 + e);
                bool keep = within && (key <= K);
                (&r0.x)[e] = keep ? sqrtf(d2) : 0.0f;
                (&r1.x)[e] = keep ? s_ct[c] : 0.0f;
                (&r2.x)[e] = keep ? 1.0f : 0.0f;
                c++; if (c == NCELLS) c = 0;
            }
            o0[g] = r0; o1[g] = r1; o2[g] = r2;
        }
    } else {
        // ---- fallback (never expected at this density) ----
        if (s_tot > MAXNB) {
            // histogram selection over s_d2 (R2-proven path)
            s_hist[tid] = 0u;
            __syncthreads();
            for (int v = tid; v < NGRP; v += BLK) {
                float4 dq = ((const float4*)s_d2)[v];
                #pragma unroll
                for (int e = 0; e < 4; e++) {
                    float d2 = (&dq.x)[e];
                    if (d2 < 64.5f) {
                        int bin = (int)(d2 * 4.0f);
                        if (bin > 255) bin = 255;
                        atomicAdd(&s_hist[bin], 1u);
                    }
                }
            }
            __syncthreads();
            unsigned h = s_hist[tid];
            int v = (int)h;
            #pragma unroll
            for (int off = 1; off < 64; off <<= 1) {
                int u = __shfl_up(v, off, 64);
                if (lane >= off) v += u;
            }
            if (lane == 63) s_wtot[w] = (unsigned)v;
            __syncthreads();
            unsigned pre = 0;
            for (int ww = 0; ww < w; ww++) pre += s_wtot[ww];
            unsigned ci = (unsigned)v + pre, ce = ci - h;
            if (h > 0 && ce < MAXNB && ci >= MAXNB) {
                s_binsel = tid;
                s_need   = MAXNB - (int)ce;
            }
            __syncthreads();
            const int binsel = s_binsel, need = s_need;
            for (int f = tid; f < NCAND; f += BLK) {
                float d2 = s_d2[f];
                if (d2 < 64.5f) {
                    int bin = (int)(d2 * 4.0f);
                    if (bin > 255) bin = 255;
                    if (bin == binsel) {
                        unsigned idx = atomicAdd(&s_cnt2, 1u);
                        if (idx < KEYCAP)
                            s_keys[idx] =
                                ((unsigned long long)__float_as_uint(d2) << 32)
                                | (unsigned)f;
                    }
                }
            }
            __syncthreads();
            const int m2 = (int)s_cnt2;
            if (m2 <= KEYCAP) {
                for (int p = tid; p < m2; p += BLK) {
                    unsigned long long kp = s_keys[p];
                    int r = 0;
                    for (int q = 0; q < m2; q++) r += (s_keys[q] < kp);
                    if (r == need - 1) s_K = kp;
                }
            } else {
                for (int f = tid; f < NCAND; f += BLK) {
                    float d2 = s_d2[f];
                    if (d2 >= 64.5f) continue;
                    int bin = (int)(d2 * 4.0f);
                    if (bin > 255) bin = 255;
                    if (bin != binsel) continue;
                    unsigned long long kf =
                        ((unsigned long long)__float_as_uint(d2) << 32)
                        | (unsigned)f;
                    int r = 0;
                    for (int q = 0; q < NCAND; q++) {
                        float dq = s_d2[q];
                        if (dq >= 64.5f) continue;
                        int bq = (int)(dq * 4.0f);
                        if (bq > 255) bq = 255;
                        if (bq != binsel) continue;
                        unsigned long long kq =
                            ((unsigned long long)__float_as_uint(dq) << 32)
                            | (unsigned)q;
                        r += (kq < kf);
                    }
                    if (r == need - 1) s_K = kf;
                }
            }
        }
        // full rewrite of ALL groups (overwrites optimistic zeros; ordered by
        // the preceding __syncthreads' vmcnt(0) drain). If s_tot<=MAXNB,
        // s_K stays ~0ULL -> keep = within (correct: no truncation).
        __syncthreads();
        const unsigned long long K = s_K;
        for (int v = tid; v < NGRP; v += BLK) {
            float4 dq = ((const float4*)s_d2)[v];
            int f0 = v * 4;
            int c = f0 % NCELLS;
            float4 r0, r1, r2;
            #pragma unroll
            for (int e = 0; e < 4; e++) {
                float d2 = (&dq.x)[e];
                bool within = (d2 <= R2);
                unsigned long long key =
                    ((unsigned long long)__float_as_uint(d2) << 32)
                    | (unsigned)(f0 + e);
                bool keep = within && (key <= K);
                (&r0.x)[e] = keep ? sqrtf(d2) : 0.0f;
                (&r1.x)[e] = keep ? s_ct[c] : 0.0f;
                (&r2.x)[e] = keep ? 1.0f : 0.0f;
                c++; if (c == NCELLS) c = 0;
            }
            o0[v] = r0; o1[v] = r1; o2[v] = r2;
        }
    }
}

// Reduce per-center clamped counts -> per-image totals (exact in f32).
__global__ __launch_bounds__(64) void reduce_counts(
    const float* __restrict__ ws_counts, float* __restrict__ out_nb)
{
    int b = blockIdx.x;
    int t = threadIdx.x;    // 64 threads
    float v = ws_counts[b * NATOMS + t] + ws_counts[b * NATOMS + 64 + t];
    for (int o = 32; o; o >>= 1) v += __shfl_down(v, o);
    if (t == 0) out_nb[b] = v;
}

extern "C" void kernel_launch(void* const* d_in, const int* in_sizes, int n_in,
                              void* d_out, int out_size, void* d_ws, size_t ws_size,
                              hipStream_t stream) {
    const float* pos  = (const float*)d_in[0];   // [32,128,3]
    const float* cell = (const float*)d_in[1];   // [32,3,3]
    float* out = (float*)d_out;
    const long long E = 32LL * NATOMS * NATOMS * NCELLS;   // 13,107,200
    float* out_dist  = out;
    float* out_ct    = out + E;
    float* out_mask  = out + 2 * E;
    float* out_nb    = out + 3 * E;                         // 32 floats
    float* ws = (float*)d_ws;                               // 4096 floats

    hipLaunchKernelGGL(graph_kernel, dim3(32 * NATOMS), dim3(BLK), 0, stream,
                       pos, cell, out_dist, out_ct, out_mask, ws);
    hipLaunchKernelGGL(reduce_counts, dim3(32), dim3(64), 0, stream,
                       ws, out_nb);
}